// Round 3
// baseline (167.714 us; speedup 1.0000x reference)
//
#include <hip/hip_runtime.h>
#include <hip/hip_cooperative_groups.h>

namespace cg = cooperative_groups;

#define KK 32
#define DD 64
#define NB 65536
#define PAD 68
#define FRAGS 6           // per-k E-tiles (bf16, 32x32x16 A order): it0:{k0,k1}, it1:{k0..k3}
#define SLOT (FRAGS * 64) // uint4 per k = 384 (6 KB)
#define MREF 103.0f       // fixed logsumexp reference (folded into Kcl2)
#define L2E 1.4426950408889634f

typedef __attribute__((ext_vector_type(8))) short bf16x8;
typedef __attribute__((ext_vector_type(4))) float f32x4;
typedef __attribute__((ext_vector_type(16))) float f32x16;

__device__ inline short f2bf(float f) {          // RNE float -> bf16 bits
  uint32_t u = __builtin_bit_cast(uint32_t, f);
  uint32_t r = (u + 0x7fffu + ((u >> 16) & 1u)) >> 16;
  return (short)(r & 0xffffu);
}
__device__ inline uint4 pack8(const short* v) {
  uint4 u;
  u.x = (uint32_t)(unsigned short)v[0] | ((uint32_t)(unsigned short)v[1] << 16);
  u.y = (uint32_t)(unsigned short)v[2] | ((uint32_t)(unsigned short)v[3] << 16);
  u.z = (uint32_t)(unsigned short)v[4] | ((uint32_t)(unsigned short)v[5] << 16);
  u.w = (uint32_t)(unsigned short)v[6] | ((uint32_t)(unsigned short)v[7] << 16);
  return u;
}

// ---------------------------------------------------------------------------
// Prep body (1 block of 256 per k): 4-sublane substitution. Packs
// E = Linv - I as 6 nonzero bf16 tiles in 32x32x16 A lane order:
//   tile (it,kt): elem j of lane t = E[i=it*32+(t&31)][m=kt*16+(t>>5)*8+j]
// Cc = Linv*mu, Kcl2 = (MREF - 0.5*d*log2pi - logdet) * log2(e).
// Shared by the fused kernel (inline) and the fallback md_prep kernel.
// ---------------------------------------------------------------------------
__device__ __forceinline__ void prep_body(int k, int t,
                                          const float* __restrict__ ls,
                                          const float* __restrict__ mu,
                                          uint4* __restrict__ Bp,
                                          float* __restrict__ Cc,
                                          float* __restrict__ Kcl2,
                                          float* Ls, float* Ys,
                                          float* invdL, float* muL) {
  const int j = t >> 2, sub = t & 3;      // column, m-residue; quartet = 4 lanes
  const float* __restrict__ lsk = ls + (size_t)k * DD * DD;

#pragma unroll
  for (int it = 0; it < 4; ++it) {
    const int o = (it * 256 + t) * 4;
    *(float4*)&Ls[o] = *(const float4*)&lsk[o];
  }
  if (t < DD) muL[t] = mu[k * DD + t];
  __syncthreads();
  if (t < DD) invdL[t] = 1.0f / (expf(Ls[t * DD + t]) + 1e-3f);
  __syncthreads();

  // column j of Linv; thread owns rows m == sub (mod 4)
  const float invdj = invdL[j];
  float z[16];
#pragma unroll
  for (int mi = 0; mi < 16; ++mi) z[mi] = 0.f;
#pragma unroll
  for (int i = 0; i < DD; ++i) {
    float p = 0.f;
#pragma unroll
    for (int mi = 0; mi < 16; ++mi) {
      if (4 * mi < i) {                         // compile-time prune
        const int m = 4 * mi + sub;
        p = fmaf(Ls[i * DD + m], (m < i) ? z[mi] : 0.f, p);
      }
    }
    p += __shfl_xor(p, 1, 64);
    p += __shfl_xor(p, 2, 64);
    const float zi = (i == j) ? invdj : -p * invdL[i];
    if (sub == (i & 3)) z[i >> 2] = zi;         // i<j: p==0 -> stores 0
  }
#pragma unroll
  for (int mi = 0; mi < 16; ++mi) Ys[(4 * mi + sub) * PAD + j] = z[mi];
  __syncthreads();

  // c_j = row j of Linv . mu
  {
    float p = 0.f;
#pragma unroll
    for (int mi = 0; mi < 16; ++mi) {
      const int m = 4 * mi + sub;
      p = fmaf(Ys[j * PAD + m], muL[m], p);
    }
    p += __shfl_xor(p, 1, 64);
    p += __shfl_xor(p, 2, 64);
    if (sub == 0) Cc[k * DD + j] = p;
  }

  // Kcl2 = (MREF - 0.5*d*log2pi - sum(log d)) * log2e
  if (t < DD) {
    float r = -logf(invdL[t]);
#pragma unroll
    for (int off = 32; off > 0; off >>= 1) r += __shfl_down(r, off, 64);
    if (t == 0)
      Kcl2[k] = (MREF - 0.5f * (64.0f * 1.83787706640934534f) - r) * L2E;
  }

  // pack the 6 nonzero bf16 E-tiles (32x32x16 A lane order)
  if (t < DD) {
    const int r32 = t & 31, h = t >> 5;
    uint4* slot = Bp + (size_t)k * SLOT;
#pragma unroll
    for (int it = 0; it < 2; ++it) {
#pragma unroll
      for (int kt = 0; kt < 4; ++kt) {
        if (it == 0 && kt >= 2) continue;        // identically-zero tiles
        const int i = it * 32 + r32;
        short hh[8];
#pragma unroll
        for (int jj = 0; jj < 8; ++jj) {
          const int m = kt * 16 + h * 8 + jj;
          const float v = Ys[i * PAD + m] - ((i == m) ? 1.0f : 0.0f);
          hh[jj] = f2bf(v);
        }
        const int fi = (it == 0) ? kt : (2 + kt); // 0,1, 2..5
        slot[fi * 64 + t] = pack8(hh);
      }
    }
  }
}

// ---------------------------------------------------------------------------
// Main-loop body for one block (128 samples x all 32 comps); wave = (sg, kg).
// R19 structure: de-staged Bp (L2-resident broadcast), barrier-free unrolled
// 16-comp loop, affine C-seed (x - c), direct global A-frag reads.
// Layouts: A m=lane&31,k=8*(lane>>5)+j; B n=lane&31,k=8*(lane>>5)+j;
// C/D col=lane&31,row=(reg&3)+8*(reg>>2)+4*(lane>>5) [m74/m101-verified].
// ---------------------------------------------------------------------------
__device__ __forceinline__ void main_tail(int tid, int sblk,
                                          const bf16x8 Xb[2][4],
                                          const f32x16 xg[2][2],
                                          const uint4* __restrict__ Bp,
                                          const float* __restrict__ Kcl2,
                                          const float* CcL, float* sOut,
                                          float* __restrict__ out) {
  const int lane = tid & 63, w = tid >> 6;
  const int sg = w & 1, kg = w >> 1;
  const int k0 = kg * 16;
  const int c32 = lane & 31, h = lane >> 5;

  float run_s[2] = {0.f, 0.f};

#pragma unroll
  for (int ci = 0; ci < 16; ++ci) {
    const int kabs = k0 + ci;
    const float kc = Kcl2[kabs];                 // uniform -> s_load
    const uint4* __restrict__ buf = Bp + (size_t)kabs * SLOT;

    // cv[it][g][r] = c[row i = it*32 + g*8 + 4h + r]
    f32x4 cv[2][4];
#pragma unroll
    for (int it = 0; it < 2; ++it)
#pragma unroll
      for (int g = 0; g < 4; ++g)
        cv[it][g] = *(const f32x4*)&CcL[kabs * DD + it * 32 + g * 8 + 4 * h];

    // A-fragments straight from global (L2/L3-hot; coalesced 16 B/lane)
    const bf16x8 A0 = *(const bf16x8*)&buf[0 * 64 + lane];
    const bf16x8 A1 = *(const bf16x8*)&buf[1 * 64 + lane];
    const bf16x8 A2 = *(const bf16x8*)&buf[2 * 64 + lane];
    const bf16x8 A3 = *(const bf16x8*)&buf[3 * 64 + lane];
    const bf16x8 A4 = *(const bf16x8*)&buf[4 * 64 + lane];
    const bf16x8 A5 = *(const bf16x8*)&buf[5 * 64 + lane];

#pragma unroll
    for (int st = 0; st < 2; ++st) {
      f32x16 acc;
#pragma unroll
      for (int it = 0; it < 2; ++it) {
        // affine seed: C = x - c (exact f32) -> chain yields z - c directly
        f32x16 z;
#pragma unroll
        for (int g = 0; g < 4; ++g) {
#pragma unroll
          for (int r = 0; r < 4; ++r)
            z[4 * g + r] = xg[it][st][4 * g + r] - cv[it][g][r];
        }
        if (it == 0) {
          z = __builtin_amdgcn_mfma_f32_32x32x16_bf16(A0, Xb[st][0], z, 0, 0, 0);
          z = __builtin_amdgcn_mfma_f32_32x32x16_bf16(A1, Xb[st][1], z, 0, 0, 0);
          acc = z * z;                           // no zero-init pass
        } else {
          z = __builtin_amdgcn_mfma_f32_32x32x16_bf16(A2, Xb[st][0], z, 0, 0, 0);
          z = __builtin_amdgcn_mfma_f32_32x32x16_bf16(A3, Xb[st][1], z, 0, 0, 0);
          z = __builtin_amdgcn_mfma_f32_32x32x16_bf16(A4, Xb[st][2], z, 0, 0, 0);
          z = __builtin_amdgcn_mfma_f32_32x32x16_bf16(A5, Xb[st][3], z, 0, 0, 0);
          acc += z * z;
        }
      }
      // pairwise tree (4-deep) + cross-half (rows split by 4h)
      const float t0 = (acc[0] + acc[1]) + (acc[2] + acc[3]);
      const float t1 = (acc[4] + acc[5]) + (acc[6] + acc[7]);
      const float t2 = (acc[8] + acc[9]) + (acc[10] + acc[11]);
      const float t3 = (acc[12] + acc[13]) + (acc[14] + acc[15]);
      float s = (t0 + t1) + (t2 + t3);
      s += __shfl_xor(s, 32, 64);
      const float tt = fmaf(-0.5f * L2E, s, kc);  // log2-domain
      run_s[st] += __builtin_amdgcn_exp2f(tt);    // == exp(t + MREF)
    }
  }

  // in-block k-half combine via LDS; write out directly
  if (h == 0) {
#pragma unroll
    for (int st = 0; st < 2; ++st)
      sOut[kg * 128 + sg * 64 + st * 32 + c32] = run_s[st];
  }
  __syncthreads();
  if (tid < 128) {
    const float S = sOut[tid] + sOut[128 + tid];
    out[sblk * 128 + tid] = logf(S) - MREF;
  }
}

// x-fragment loads (registers): Xb bf16 B-frags + xg exact-f32 C/D seeds
__device__ __forceinline__ void load_x_frags(const float* __restrict__ x,
                                             int base, int lane,
                                             bf16x8 Xb[2][4], f32x16 xg[2][2]) {
  const int c32 = lane & 31, h = lane >> 5;
#pragma unroll
  for (int st = 0; st < 2; ++st) {
#pragma unroll
    for (int kt = 0; kt < 4; ++kt) {
      const float* src = x + (size_t)(base + st * 32 + c32) * DD + kt * 16 + h * 8;
      const float4 v0 = *(const float4*)src;
      const float4 v1 = *(const float4*)(src + 4);
      const float f[8] = {v0.x, v0.y, v0.z, v0.w, v1.x, v1.y, v1.z, v1.w};
      bf16x8 hb;
#pragma unroll
      for (int jj = 0; jj < 8; ++jj) hb[jj] = f2bf(f[jj]);
      Xb[st][kt] = hb;
    }
  }
#pragma unroll
  for (int it = 0; it < 2; ++it)
#pragma unroll
    for (int st = 0; st < 2; ++st)
#pragma unroll
      for (int g = 0; g < 4; ++g) {
        const f32x4 v = *(const f32x4*)&x[(size_t)(base + st * 32 + c32) * DD +
                                          it * 32 + g * 8 + 4 * h];
        xg[it][st][4 * g + 0] = v[0];
        xg[it][st][4 * g + 1] = v[1];
        xg[it][st][4 * g + 2] = v[2];
        xg[it][st][4 * g + 3] = v[3];
      }
}

// ---------------------------------------------------------------------------
// R20: cooperative fusion. 512 blocks (exactly 2/CU co-resident). Blocks 0..31
// run prep (~3.5 us on 32 CUs) WHILE all 512 blocks do their HBM-bound x-load
// (~2.6 us) -> prep hides under the load instead of serializing before it;
// one launch gap removed. grid.sync() publishes Bp/Cc/Kcl2 (device-scope
// fence semantics), then the R19 barrier-free main loop runs unchanged.
// Bit-identical math. LDS = prep(34K) + CcL(8K) + sOut(1K) ~ 43.5 KB -> 2/CU ok.
// ---------------------------------------------------------------------------
__global__ __launch_bounds__(256, 2) void md_fused(const float* __restrict__ x,
                                                   const float* __restrict__ ls,
                                                   const float* __restrict__ mu,
                                                   uint4* __restrict__ Bp,
                                                   float* __restrict__ Cc,
                                                   float* __restrict__ Kcl2,
                                                   float* __restrict__ out) {
  __shared__ float Ls[DD * DD];
  __shared__ float Ys[DD * PAD];
  __shared__ float invdL[DD];
  __shared__ float muL[DD];
  __shared__ float CcL[KK * DD];
  __shared__ float sOut[2 * 128];
  const int tid = threadIdx.x, lane = tid & 63, w = tid >> 6;
  const int sblk = blockIdx.x;
  const int base = sblk * 128 + (w & 1) * 64;

  if (sblk < KK)
    prep_body(sblk, tid, ls, mu, Bp, Cc, Kcl2, Ls, Ys, invdL, muL);

  bf16x8 Xb[2][4];
  f32x16 xg[2][2];
  load_x_frags(x, base, lane, Xb, xg);

  if (sblk < KK) __threadfence();                // publish prep writes
  cg::this_grid().sync();                        // device-scope barrier

  // stage ALL 32 c vectors into LDS (2048 floats, coalesced)
#pragma unroll
  for (int it = 0; it < 8; ++it)
    CcL[it * 256 + tid] = Cc[it * 256 + tid];
  __syncthreads();

  main_tail(tid, sblk, Xb, xg, Bp, Kcl2, CcL, sOut, out);
}

// --------------------------- fallback kernels ------------------------------
__global__ __launch_bounds__(256) void md_prep(const float* __restrict__ ls,
                                               const float* __restrict__ mu,
                                               uint4* __restrict__ Bp,
                                               float* __restrict__ Cc,
                                               float* __restrict__ Kcl2) {
  __shared__ float Ls[DD * DD];
  __shared__ float Ys[DD * PAD];
  __shared__ float invdL[DD];
  __shared__ float muL[DD];
  prep_body(blockIdx.x, threadIdx.x, ls, mu, Bp, Cc, Kcl2, Ls, Ys, invdL, muL);
}

__global__ __launch_bounds__(256, 2) void md_main(const float* __restrict__ x,
                                                  const uint4* __restrict__ Bp,
                                                  const float* __restrict__ Cc,
                                                  const float* __restrict__ Kcl2,
                                                  float* __restrict__ out) {
  __shared__ float CcL[KK * DD];
  __shared__ float sOut[2 * 128];
  const int tid = threadIdx.x, lane = tid & 63, w = tid >> 6;
  const int sblk = blockIdx.x;
  const int base = sblk * 128 + (w & 1) * 64;

  bf16x8 Xb[2][4];
  f32x16 xg[2][2];
  load_x_frags(x, base, lane, Xb, xg);

#pragma unroll
  for (int it = 0; it < 8; ++it)
    CcL[it * 256 + tid] = Cc[it * 256 + tid];
  __syncthreads();

  main_tail(tid, sblk, Xb, xg, Bp, Kcl2, CcL, sOut, out);
}

extern "C" void kernel_launch(void* const* d_in, const int* in_sizes, int n_in,
                              void* d_out, int out_size, void* d_ws, size_t ws_size,
                              hipStream_t stream) {
  const float* x  = (const float*)d_in[0];
  // d_in[1] = log_pi: softmax over size-1 axis == 1.0 -> unused.
  const float* mu = (const float*)d_in[2];
  const float* ls = (const float*)d_in[3];
  float* out = (float*)d_out;

  char* ws = (char*)d_ws;
  uint4* Bp   = (uint4*)ws;                            // 32 * 6 KB = 192 KB
  float* Cc   = (float*)(ws + (size_t)KK * SLOT * 16); // 8 KB
  float* Kcl2 = Cc + KK * DD;                          // 128 B

  void* args[] = {(void*)&x, (void*)&ls, (void*)&mu, (void*)&Bp,
                  (void*)&Cc, (void*)&Kcl2, (void*)&out};
  hipError_t e = hipLaunchCooperativeKernel((const void*)md_fused,
                                            dim3(NB / 128), dim3(256),
                                            args, 0, stream);
  if (e != hipSuccess) {                               // capture-safe fallback
    md_prep<<<KK, 256, 0, stream>>>(ls, mu, Bp, Cc, Kcl2);
    md_main<<<NB / 128, 256, 0, stream>>>(x, Bp, Cc, Kcl2, out);
  }
}

// Round 7
// 100.536 us; speedup vs baseline: 1.6682x; 1.6682x over previous
//
#include <hip/hip_runtime.h>

#define KK 32
#define DD 64
#define NB 65536
#define PAD 68
#define FRAGS 6           // per-k E-tiles (bf16, 32x32x16 A order): it0:{k0,k1}, it1:{k0..k3}
#define SLOT (FRAGS * 64) // uint4 per k = 384 (6 KB)
#define MREF 103.0f       // fixed logsumexp reference (folded into Kcl2)
#define L2E 1.4426950408889634f

typedef __attribute__((ext_vector_type(8))) short bf16x8;
typedef __attribute__((ext_vector_type(4))) float f32x4;
typedef __attribute__((ext_vector_type(16))) float f32x16;

__device__ inline short f2bf(float f) {          // RNE float -> bf16 bits
  uint32_t u = __builtin_bit_cast(uint32_t, f);
  uint32_t r = (u + 0x7fffu + ((u >> 16) & 1u)) >> 16;
  return (short)(r & 0xffffu);
}
__device__ inline uint4 pack8(const short* v) {
  uint4 u;
  u.x = (uint32_t)(unsigned short)v[0] | ((uint32_t)(unsigned short)v[1] << 16);
  u.y = (uint32_t)(unsigned short)v[2] | ((uint32_t)(unsigned short)v[3] << 16);
  u.z = (uint32_t)(unsigned short)v[4] | ((uint32_t)(unsigned short)v[5] << 16);
  u.w = (uint32_t)(unsigned short)v[6] | ((uint32_t)(unsigned short)v[7] << 16);
  return u;
}

// ---------------------------------------------------------------------------
// Prep (1 block of 256 per k): 4-sublane substitution. Packs
// E = Linv - I as 6 nonzero bf16 tiles in 32x32x16 A lane order:
//   tile (it,kt): elem j of lane t = E[i=it*32+(t&31)][m=kt*16+(t>>5)*8+j]
//   fi = kt (it=0, kt<2) / 2+kt (it=1).  E lower-tri: it0 x kt>=2 == 0.
// Cc = Linv*mu, Kcl2 = (MREF - 0.5*d*log2pi - logdet) * log2(e).
// R21 note: cooperative fusion (R20) REGRESSED 69 us — grid.sync() on gfx950
// costs ~80 us (cross-XCD spin; counters: 3.6% HBM, 5% Mfma, 10% VALU).
// Two plain kernels on one stream are the right structure here.
// ---------------------------------------------------------------------------
__global__ __launch_bounds__(256) void md_prep(const float* __restrict__ ls,
                                               const float* __restrict__ mu,
                                               uint4* __restrict__ Bp,
                                               float* __restrict__ Cc,
                                               float* __restrict__ Kcl2) {
  __shared__ float Ls[DD * DD];
  __shared__ float Ys[DD * PAD];
  __shared__ float invdL[DD];
  __shared__ float muL[DD];
  const int k = blockIdx.x, t = threadIdx.x;
  const int j = t >> 2, sub = t & 3;      // column, m-residue; quartet = 4 lanes
  const float* __restrict__ lsk = ls + (size_t)k * DD * DD;

#pragma unroll
  for (int it = 0; it < 4; ++it) {
    const int o = (it * 256 + t) * 4;
    *(float4*)&Ls[o] = *(const float4*)&lsk[o];
  }
  if (t < DD) muL[t] = mu[k * DD + t];
  __syncthreads();
  if (t < DD) invdL[t] = 1.0f / (expf(Ls[t * DD + t]) + 1e-3f);
  __syncthreads();

  // column j of Linv; thread owns rows m == sub (mod 4)
  const float invdj = invdL[j];
  float z[16];
#pragma unroll
  for (int mi = 0; mi < 16; ++mi) z[mi] = 0.f;
#pragma unroll
  for (int i = 0; i < DD; ++i) {
    float p = 0.f;
#pragma unroll
    for (int mi = 0; mi < 16; ++mi) {
      if (4 * mi < i) {                         // compile-time prune
        const int m = 4 * mi + sub;
        p = fmaf(Ls[i * DD + m], (m < i) ? z[mi] : 0.f, p);
      }
    }
    p += __shfl_xor(p, 1, 64);
    p += __shfl_xor(p, 2, 64);
    const float zi = (i == j) ? invdj : -p * invdL[i];
    if (sub == (i & 3)) z[i >> 2] = zi;         // i<j: p==0 -> stores 0
  }
#pragma unroll
  for (int mi = 0; mi < 16; ++mi) Ys[(4 * mi + sub) * PAD + j] = z[mi];
  __syncthreads();

  // c_j = row j of Linv . mu
  {
    float p = 0.f;
#pragma unroll
    for (int mi = 0; mi < 16; ++mi) {
      const int m = 4 * mi + sub;
      p = fmaf(Ys[j * PAD + m], muL[m], p);
    }
    p += __shfl_xor(p, 1, 64);
    p += __shfl_xor(p, 2, 64);
    if (sub == 0) Cc[k * DD + j] = p;
  }

  // Kcl2 = (MREF - 0.5*d*log2pi - sum(log d)) * log2e
  if (t < DD) {
    float r = -logf(invdL[t]);
#pragma unroll
    for (int off = 32; off > 0; off >>= 1) r += __shfl_down(r, off, 64);
    if (t == 0)
      Kcl2[k] = (MREF - 0.5f * (64.0f * 1.83787706640934534f) - r) * L2E;
  }

  // pack the 6 nonzero bf16 E-tiles (32x32x16 A lane order)
  if (t < DD) {
    const int r32 = t & 31, h = t >> 5;
    uint4* slot = Bp + (size_t)k * SLOT;
#pragma unroll
    for (int it = 0; it < 2; ++it) {
#pragma unroll
      for (int kt = 0; kt < 4; ++kt) {
        if (it == 0 && kt >= 2) continue;        // identically-zero tiles
        const int i = it * 32 + r32;
        short hh[8];
#pragma unroll
        for (int jj = 0; jj < 8; ++jj) {
          const int m = kt * 16 + h * 8 + jj;
          const float v = Ys[i * PAD + m] - ((i == m) ? 1.0f : 0.0f);
          hh[jj] = f2bf(v);
        }
        const int fi = (it == 0) ? kt : (2 + kt); // 0,1, 2..5
        slot[fi * 64 + t] = pack8(hh);
      }
    }
  }
}

// ---------------------------------------------------------------------------
// Main: 512 blocks x (128 samples x all 32 comps); wave = (sg, kg).
// R19 structure (best verified): de-staged Bp (L2-resident broadcast),
// barrier-free unrolled 16-comp loop, affine C-seed (x - c), direct global
// A-frag reads. R21: also de-stage Cc (8 KB broadcast -> L1/L2-hot direct
// f32x4 reads; removes staging loads + ds_writes + the last pre-loop
// __syncthreads + 128 ds_reads per block). LDS now just the 1 KB sOut.
// Math/summation order unchanged -> bit-identical output.
// Layouts: A m=lane&31,k=8*(lane>>5)+j; B n=lane&31,k=8*(lane>>5)+j;
// C/D col=lane&31,row=(reg&3)+8*(reg>>2)+4*(lane>>5) [m74/m101-verified].
// ---------------------------------------------------------------------------
__global__ __launch_bounds__(256, 2) void md_main(const float* __restrict__ x,
                                                  const uint4* __restrict__ Bp,
                                                  const float* __restrict__ Cc,
                                                  const float* __restrict__ Kcl2,
                                                  float* __restrict__ out) {
  __shared__ float sOut[2 * 128];    // k-half partials for the 128 samples
  const int tid = threadIdx.x, lane = tid & 63, w = tid >> 6;
  const int sg = w & 1, kg = w >> 1;
  const int sblk = blockIdx.x;
  const int base = sblk * 128 + sg * 64;
  const int k0 = kg * 16;
  const int c32 = lane & 31, h = lane >> 5;

  // B-frags (x): Xb[st][kt] elem j = x[base+st*32+c32][kt*16+h*8+j]
  bf16x8 Xb[2][4];
#pragma unroll
  for (int st = 0; st < 2; ++st) {
#pragma unroll
    for (int kt = 0; kt < 4; ++kt) {
      const float* src = x + (size_t)(base + st * 32 + c32) * DD + kt * 16 + h * 8;
      const float4 v0 = *(const float4*)src;
      const float4 v1 = *(const float4*)(src + 4);
      const float f[8] = {v0.x, v0.y, v0.z, v0.w, v1.x, v1.y, v1.z, v1.w};
      bf16x8 hb;
#pragma unroll
      for (int jj = 0; jj < 8; ++jj) hb[jj] = f2bf(f[jj]);
      Xb[st][kt] = hb;
    }
  }

  // f32 x^T seed in C/D layout: xg[it][st][reg], reg=g*4+r ->
  // row i = it*32 + r + 8g + 4h, col n = base+st*32+c32 (L1-hot re-read)
  f32x16 xg[2][2];
#pragma unroll
  for (int it = 0; it < 2; ++it)
#pragma unroll
    for (int st = 0; st < 2; ++st)
#pragma unroll
      for (int g = 0; g < 4; ++g) {
        const f32x4 v = *(const f32x4*)&x[(size_t)(base + st * 32 + c32) * DD +
                                          it * 32 + g * 8 + 4 * h];
        xg[it][st][4 * g + 0] = v[0];
        xg[it][st][4 * g + 1] = v[1];
        xg[it][st][4 * g + 2] = v[2];
        xg[it][st][4 * g + 3] = v[3];
      }

  float run_s[2] = {0.f, 0.f};

#pragma unroll
  for (int ci = 0; ci < 16; ++ci) {
    const int kabs = k0 + ci;                    // same order as before
    const float kc = Kcl2[kabs];                 // wave-uniform -> s_load
    const uint4* __restrict__ buf = Bp + (size_t)kabs * SLOT;

    // cv[it][g][r] = c[row i = it*32 + g*8 + 4h + r] — direct from global
    // (8 KB broadcast, L1/L2-hot; 2 cachelines per wave access)
    f32x4 cv[2][4];
#pragma unroll
    for (int it = 0; it < 2; ++it)
#pragma unroll
      for (int g = 0; g < 4; ++g)
        cv[it][g] = *(const f32x4*)&Cc[kabs * DD + it * 32 + g * 8 + 4 * h];

    // A-fragments straight from global (L2/L3-hot; coalesced 16 B/lane)
    const bf16x8 A0 = *(const bf16x8*)&buf[0 * 64 + lane];
    const bf16x8 A1 = *(const bf16x8*)&buf[1 * 64 + lane];
    const bf16x8 A2 = *(const bf16x8*)&buf[2 * 64 + lane];
    const bf16x8 A3 = *(const bf16x8*)&buf[3 * 64 + lane];
    const bf16x8 A4 = *(const bf16x8*)&buf[4 * 64 + lane];
    const bf16x8 A5 = *(const bf16x8*)&buf[5 * 64 + lane];

#pragma unroll
    for (int st = 0; st < 2; ++st) {
      f32x16 acc;
#pragma unroll
      for (int it = 0; it < 2; ++it) {
        // affine seed: C = x - c (exact f32) -> chain yields z - c directly
        f32x16 z;
#pragma unroll
        for (int g = 0; g < 4; ++g) {
#pragma unroll
          for (int r = 0; r < 4; ++r)
            z[4 * g + r] = xg[it][st][4 * g + r] - cv[it][g][r];
        }
        if (it == 0) {
          z = __builtin_amdgcn_mfma_f32_32x32x16_bf16(A0, Xb[st][0], z, 0, 0, 0);
          z = __builtin_amdgcn_mfma_f32_32x32x16_bf16(A1, Xb[st][1], z, 0, 0, 0);
          acc = z * z;                           // no zero-init pass
        } else {
          z = __builtin_amdgcn_mfma_f32_32x32x16_bf16(A2, Xb[st][0], z, 0, 0, 0);
          z = __builtin_amdgcn_mfma_f32_32x32x16_bf16(A3, Xb[st][1], z, 0, 0, 0);
          z = __builtin_amdgcn_mfma_f32_32x32x16_bf16(A4, Xb[st][2], z, 0, 0, 0);
          z = __builtin_amdgcn_mfma_f32_32x32x16_bf16(A5, Xb[st][3], z, 0, 0, 0);
          acc += z * z;
        }
      }
      // pairwise tree (4-deep) + cross-half (rows split by 4h)
      const float t0 = (acc[0] + acc[1]) + (acc[2] + acc[3]);
      const float t1 = (acc[4] + acc[5]) + (acc[6] + acc[7]);
      const float t2 = (acc[8] + acc[9]) + (acc[10] + acc[11]);
      const float t3 = (acc[12] + acc[13]) + (acc[14] + acc[15]);
      float s = (t0 + t1) + (t2 + t3);
      s += __shfl_xor(s, 32, 64);
      const float tt = fmaf(-0.5f * L2E, s, kc);  // log2-domain
      run_s[st] += __builtin_amdgcn_exp2f(tt);    // == exp(t + MREF)
    }
  }

  // in-block k-half combine via LDS; write out directly
  if (h == 0) {
#pragma unroll
    for (int st = 0; st < 2; ++st)
      sOut[kg * 128 + sg * 64 + st * 32 + c32] = run_s[st];
  }
  __syncthreads();
  if (tid < 128) {
    const float S = sOut[tid] + sOut[128 + tid];
    out[sblk * 128 + tid] = logf(S) - MREF;
  }
}

extern "C" void kernel_launch(void* const* d_in, const int* in_sizes, int n_in,
                              void* d_out, int out_size, void* d_ws, size_t ws_size,
                              hipStream_t stream) {
  const float* x  = (const float*)d_in[0];
  // d_in[1] = log_pi: softmax over size-1 axis == 1.0 -> unused.
  const float* mu = (const float*)d_in[2];
  const float* ls = (const float*)d_in[3];
  float* out = (float*)d_out;

  char* ws = (char*)d_ws;
  uint4* Bp   = (uint4*)ws;                            // 32 * 6 KB = 192 KB
  float* Cc   = (float*)(ws + (size_t)KK * SLOT * 16); // 8 KB
  float* Kcl2 = Cc + KK * DD;                          // 128 B

  md_prep<<<KK, 256, 0, stream>>>(ls, mu, Bp, Cc, Kcl2);
  md_main<<<NB / 128, 256, 0, stream>>>(x, Bp, Cc, Kcl2, out);
}

// Round 9
// 97.982 us; speedup vs baseline: 1.7117x; 1.0261x over previous
//
#include <hip/hip_runtime.h>

#define KK 32
#define DD 64
#define NB 65536
#define PAD 68
#define FRAGS 6           // per-k E-tiles (bf16, 32x32x16 A order): it0:{k0,k1}, it1:{k0..k3}
#define SLOT (FRAGS * 64) // uint4 per k = 384 (6 KB)
#define MREF 103.0f       // fixed logsumexp reference (folded into Kcl2)
#define L2E 1.4426950408889634f

typedef __attribute__((ext_vector_type(8))) short bf16x8;
typedef __attribute__((ext_vector_type(4))) float f32x4;
typedef __attribute__((ext_vector_type(16))) float f32x16;

__device__ inline short f2bf(float f) {          // RNE float -> bf16 bits
  uint32_t u = __builtin_bit_cast(uint32_t, f);
  uint32_t r = (u + 0x7fffu + ((u >> 16) & 1u)) >> 16;
  return (short)(r & 0xffffu);
}
__device__ inline uint4 pack8(const short* v) {
  uint4 u;
  u.x = (uint32_t)(unsigned short)v[0] | ((uint32_t)(unsigned short)v[1] << 16);
  u.y = (uint32_t)(unsigned short)v[2] | ((uint32_t)(unsigned short)v[3] << 16);
  u.z = (uint32_t)(unsigned short)v[4] | ((uint32_t)(unsigned short)v[5] << 16);
  u.w = (uint32_t)(unsigned short)v[6] | ((uint32_t)(unsigned short)v[7] << 16);
  return u;
}

// ---------------------------------------------------------------------------
// Prep (1 block of 256 per k): 4-sublane substitution. Packs
// E = Linv - I as 6 nonzero bf16 tiles in 32x32x16 A lane order:
//   tile (it,kt): elem j of lane t = E[i=it*32+(t&31)][m=kt*16+(t>>5)*8+j]
//   fi = kt (it=0, kt<2) / 2+kt (it=1).  E lower-tri: it0 x kt>=2 == 0.
// Cc = Linv*mu, Kcl2 = (MREF - 0.5*d*log2pi - logdet) * log2(e).
// Session ledger: R20 cooperative fusion REGRESSED 69 us (grid.sync ~80 us on
// gfx950, cross-XCD spin). R21 Cc-de-staging: no win (100.5 vs 98.7, within
// fill-noise but trending worse — LDS staging of a 16x-reused operand is
// cheaper than L1 loads on the critical path). This is the R19 best-measured
// configuration (98.67 us).
// ---------------------------------------------------------------------------
__global__ __launch_bounds__(256) void md_prep(const float* __restrict__ ls,
                                               const float* __restrict__ mu,
                                               uint4* __restrict__ Bp,
                                               float* __restrict__ Cc,
                                               float* __restrict__ Kcl2) {
  __shared__ float Ls[DD * DD];
  __shared__ float Ys[DD * PAD];
  __shared__ float invdL[DD];
  __shared__ float muL[DD];
  const int k = blockIdx.x, t = threadIdx.x;
  const int j = t >> 2, sub = t & 3;      // column, m-residue; quartet = 4 lanes
  const float* __restrict__ lsk = ls + (size_t)k * DD * DD;

#pragma unroll
  for (int it = 0; it < 4; ++it) {
    const int o = (it * 256 + t) * 4;
    *(float4*)&Ls[o] = *(const float4*)&lsk[o];
  }
  if (t < DD) muL[t] = mu[k * DD + t];
  __syncthreads();
  if (t < DD) invdL[t] = 1.0f / (expf(Ls[t * DD + t]) + 1e-3f);
  __syncthreads();

  // column j of Linv; thread owns rows m == sub (mod 4)
  const float invdj = invdL[j];
  float z[16];
#pragma unroll
  for (int mi = 0; mi < 16; ++mi) z[mi] = 0.f;
#pragma unroll
  for (int i = 0; i < DD; ++i) {
    float p = 0.f;
#pragma unroll
    for (int mi = 0; mi < 16; ++mi) {
      if (4 * mi < i) {                         // compile-time prune
        const int m = 4 * mi + sub;
        p = fmaf(Ls[i * DD + m], (m < i) ? z[mi] : 0.f, p);
      }
    }
    p += __shfl_xor(p, 1, 64);
    p += __shfl_xor(p, 2, 64);
    const float zi = (i == j) ? invdj : -p * invdL[i];
    if (sub == (i & 3)) z[i >> 2] = zi;         // i<j: p==0 -> stores 0
  }
#pragma unroll
  for (int mi = 0; mi < 16; ++mi) Ys[(4 * mi + sub) * PAD + j] = z[mi];
  __syncthreads();

  // c_j = row j of Linv . mu
  {
    float p = 0.f;
#pragma unroll
    for (int mi = 0; mi < 16; ++mi) {
      const int m = 4 * mi + sub;
      p = fmaf(Ys[j * PAD + m], muL[m], p);
    }
    p += __shfl_xor(p, 1, 64);
    p += __shfl_xor(p, 2, 64);
    if (sub == 0) Cc[k * DD + j] = p;
  }

  // Kcl2 = (MREF - 0.5*d*log2pi - sum(log d)) * log2e
  if (t < DD) {
    float r = -logf(invdL[t]);
#pragma unroll
    for (int off = 32; off > 0; off >>= 1) r += __shfl_down(r, off, 64);
    if (t == 0)
      Kcl2[k] = (MREF - 0.5f * (64.0f * 1.83787706640934534f) - r) * L2E;
  }

  // pack the 6 nonzero bf16 E-tiles (32x32x16 A lane order)
  if (t < DD) {
    const int r32 = t & 31, h = t >> 5;
    uint4* slot = Bp + (size_t)k * SLOT;
#pragma unroll
    for (int it = 0; it < 2; ++it) {
#pragma unroll
      for (int kt = 0; kt < 4; ++kt) {
        if (it == 0 && kt >= 2) continue;        // identically-zero tiles
        const int i = it * 32 + r32;
        short hh[8];
#pragma unroll
        for (int jj = 0; jj < 8; ++jj) {
          const int m = kt * 16 + h * 8 + jj;
          const float v = Ys[i * PAD + m] - ((i == m) ? 1.0f : 0.0f);
          hh[jj] = f2bf(v);
        }
        const int fi = (it == 0) ? kt : (2 + kt); // 0,1, 2..5
        slot[fi * 64 + t] = pack8(hh);
      }
    }
  }
}

// ---------------------------------------------------------------------------
// Main: 512 blocks x (128 samples x all 32 comps); wave = (sg, kg).
// R19 best-measured structure: de-staged Bp (L2-resident broadcast read
// direct from global), Cc staged in LDS (16x-reused per wave -> ds_read
// beats L1 latency; R21 falsified the de-stage), barrier-free unrolled
// 16-comp loop, affine C-seed (x - c), hoisted A-frags, pairwise reduction,
// raw v_exp_f32.
// Layouts: A m=lane&31,k=8*(lane>>5)+j; B n=lane&31,k=8*(lane>>5)+j;
// C/D col=lane&31,row=(reg&3)+8*(reg>>2)+4*(lane>>5) [m74/m101-verified].
// ---------------------------------------------------------------------------
__global__ __launch_bounds__(256, 2) void md_main(const float* __restrict__ x,
                                                  const uint4* __restrict__ Bp,
                                                  const float* __restrict__ Cc,
                                                  const float* __restrict__ Kcl2,
                                                  float* __restrict__ out) {
  __shared__ float CcL[KK * DD];     // all 32 c vectors (8 KB)
  __shared__ float sOut[2 * 128];    // k-half partials for the 128 samples
  const int tid = threadIdx.x, lane = tid & 63, w = tid >> 6;
  const int sg = w & 1, kg = w >> 1;
  const int sblk = blockIdx.x;
  const int base = sblk * 128 + sg * 64;
  const int k0 = kg * 16;
  const int c32 = lane & 31, h = lane >> 5;

  // B-frags (x): Xb[st][kt] elem j = x[base+st*32+c32][kt*16+h*8+j]
  bf16x8 Xb[2][4];
#pragma unroll
  for (int st = 0; st < 2; ++st) {
#pragma unroll
    for (int kt = 0; kt < 4; ++kt) {
      const float* src = x + (size_t)(base + st * 32 + c32) * DD + kt * 16 + h * 8;
      const float4 v0 = *(const float4*)src;
      const float4 v1 = *(const float4*)(src + 4);
      const float f[8] = {v0.x, v0.y, v0.z, v0.w, v1.x, v1.y, v1.z, v1.w};
      bf16x8 hb;
#pragma unroll
      for (int jj = 0; jj < 8; ++jj) hb[jj] = f2bf(f[jj]);
      Xb[st][kt] = hb;
    }
  }

  // f32 x^T seed in C/D layout: xg[it][st][reg], reg=g*4+r ->
  // row i = it*32 + r + 8g + 4h, col n = base+st*32+c32 (L1-hot re-read)
  f32x16 xg[2][2];
#pragma unroll
  for (int it = 0; it < 2; ++it)
#pragma unroll
    for (int st = 0; st < 2; ++st)
#pragma unroll
      for (int g = 0; g < 4; ++g) {
        const f32x4 v = *(const f32x4*)&x[(size_t)(base + st * 32 + c32) * DD +
                                          it * 32 + g * 8 + 4 * h];
        xg[it][st][4 * g + 0] = v[0];
        xg[it][st][4 * g + 1] = v[1];
        xg[it][st][4 * g + 2] = v[2];
        xg[it][st][4 * g + 3] = v[3];
      }

  // stage ALL 32 c vectors into LDS (2048 floats, coalesced)
#pragma unroll
  for (int it = 0; it < 8; ++it)
    CcL[it * 256 + tid] = Cc[it * 256 + tid];
  __syncthreads();

  float run_s[2] = {0.f, 0.f};

#pragma unroll
  for (int ci = 0; ci < 16; ++ci) {
    const int kabs = k0 + ci;                    // same order as before
    const float kc = Kcl2[kabs];                 // wave-uniform -> s_load
    const uint4* __restrict__ buf = Bp + (size_t)kabs * SLOT;

    // cv[it][g][r] = c[row i = it*32 + g*8 + 4h + r] — from LDS
    f32x4 cv[2][4];
#pragma unroll
    for (int it = 0; it < 2; ++it)
#pragma unroll
      for (int g = 0; g < 4; ++g)
        cv[it][g] = *(const f32x4*)&CcL[kabs * DD + it * 32 + g * 8 + 4 * h];

    // A-fragments straight from global (L2/L3-hot; coalesced 16 B/lane)
    const bf16x8 A0 = *(const bf16x8*)&buf[0 * 64 + lane];
    const bf16x8 A1 = *(const bf16x8*)&buf[1 * 64 + lane];
    const bf16x8 A2 = *(const bf16x8*)&buf[2 * 64 + lane];
    const bf16x8 A3 = *(const bf16x8*)&buf[3 * 64 + lane];
    const bf16x8 A4 = *(const bf16x8*)&buf[4 * 64 + lane];
    const bf16x8 A5 = *(const bf16x8*)&buf[5 * 64 + lane];

#pragma unroll
    for (int st = 0; st < 2; ++st) {
      f32x16 acc;
#pragma unroll
      for (int it = 0; it < 2; ++it) {
        // affine seed: C = x - c (exact f32) -> chain yields z - c directly
        f32x16 z;
#pragma unroll
        for (int g = 0; g < 4; ++g) {
#pragma unroll
          for (int r = 0; r < 4; ++r)
            z[4 * g + r] = xg[it][st][4 * g + r] - cv[it][g][r];
        }
        if (it == 0) {
          z = __builtin_amdgcn_mfma_f32_32x32x16_bf16(A0, Xb[st][0], z, 0, 0, 0);
          z = __builtin_amdgcn_mfma_f32_32x32x16_bf16(A1, Xb[st][1], z, 0, 0, 0);
          acc = z * z;                           // no zero-init pass
        } else {
          z = __builtin_amdgcn_mfma_f32_32x32x16_bf16(A2, Xb[st][0], z, 0, 0, 0);
          z = __builtin_amdgcn_mfma_f32_32x32x16_bf16(A3, Xb[st][1], z, 0, 0, 0);
          z = __builtin_amdgcn_mfma_f32_32x32x16_bf16(A4, Xb[st][2], z, 0, 0, 0);
          z = __builtin_amdgcn_mfma_f32_32x32x16_bf16(A5, Xb[st][3], z, 0, 0, 0);
          acc += z * z;
        }
      }
      // pairwise tree (4-deep) + cross-half (rows split by 4h)
      const float t0 = (acc[0] + acc[1]) + (acc[2] + acc[3]);
      const float t1 = (acc[4] + acc[5]) + (acc[6] + acc[7]);
      const float t2 = (acc[8] + acc[9]) + (acc[10] + acc[11]);
      const float t3 = (acc[12] + acc[13]) + (acc[14] + acc[15]);
      float s = (t0 + t1) + (t2 + t3);
      s += __shfl_xor(s, 32, 64);
      const float tt = fmaf(-0.5f * L2E, s, kc);  // log2-domain
      run_s[st] += __builtin_amdgcn_exp2f(tt);    // == exp(t + MREF)
    }
  }

  // in-block k-half combine via LDS; write out directly
  if (h == 0) {
#pragma unroll
    for (int st = 0; st < 2; ++st)
      sOut[kg * 128 + sg * 64 + st * 32 + c32] = run_s[st];
  }
  __syncthreads();
  if (tid < 128) {
    const float S = sOut[tid] + sOut[128 + tid];
    out[sblk * 128 + tid] = logf(S) - MREF;
  }
}

extern "C" void kernel_launch(void* const* d_in, const int* in_sizes, int n_in,
                              void* d_out, int out_size, void* d_ws, size_t ws_size,
                              hipStream_t stream) {
  const float* x  = (const float*)d_in[0];
  // d_in[1] = log_pi: softmax over size-1 axis == 1.0 -> unused.
  const float* mu = (const float*)d_in[2];
  const float* ls = (const float*)d_in[3];
  float* out = (float*)d_out;

  char* ws = (char*)d_ws;
  uint4* Bp   = (uint4*)ws;                            // 32 * 6 KB = 192 KB
  float* Cc   = (float*)(ws + (size_t)KK * SLOT * 16); // 8 KB
  float* Kcl2 = Cc + KK * DD;                          // 128 B

  md_prep<<<KK, 256, 0, stream>>>(ls, mu, Bp, Cc, Kcl2);
  md_main<<<NB / 128, 256, 0, stream>>>(x, Bp, Cc, Kcl2, out);
}